// Round 3
// baseline (773.142 us; speedup 1.0000x reference)
//
#include <hip/hip_runtime.h>

#define NVEH 8192
#define NT   512
#define G    2   // vehicle groups (of 16) per block, interleaved in-wave

typedef short bf16x8 __attribute__((ext_vector_type(8)));
typedef float f32x4  __attribute__((ext_vector_type(4)));

__device__ __forceinline__ float fsig(float x) {
    float e = __builtin_amdgcn_exp2f(-1.44269504f * x);
    return __builtin_amdgcn_rcpf(1.0f + e);
}
__device__ __forceinline__ float ftanh(float x) {
    float e = __builtin_amdgcn_exp2f(-2.88539008f * x);
    return 2.0f * __builtin_amdgcn_rcpf(1.0f + e) - 1.0f;
}
__device__ __forceinline__ unsigned short f2bf(float f) {
    union { float f; unsigned u; } vv; vv.f = f;
    unsigned r = vv.u + 0x7fff + ((vv.u >> 16) & 1);
    return (unsigned short)(r >> 16);
}
// HW packed f32->bf16 (RNE), one instr for two converts + pack.
__device__ __forceinline__ unsigned cvtpk_bf16(float lo, float hi) {
    unsigned r;
    asm("v_cvt_pk_bf16_f32 %0, %1, %2" : "=v"(r) : "v"(lo), "v"(hi));
    return r;
}

// LDS-only barrier: order ds ops across waves WITHOUT draining vmcnt.
__device__ __forceinline__ void lds_barrier() {
    asm volatile("s_waitcnt lgkmcnt(0)" ::: "memory");
    __builtin_amdgcn_s_barrier();
    asm volatile("" ::: "memory");
}

// 4 waves per block; each block owns G=2 groups of 16 vehicles, interleaved
// inside the same waves (fills each wave's latency stalls with the other
// group's independent chain; 256 blocks -> 1 block/CU, 1 wave/SIMD, no
// cross-block SIMD time-sharing).
//   w0: z-tiles 0,1 (units 0..7)   w1: z-tiles 2,3 (units 8..15)
//   w2: z-tile 4   (units 16..19)
//   w3: post-barrier: head MFMA + lc + store + x-pack(t+2) + prefetch.
__global__ __launch_bounds__(256) void lstm_scan_kernel(
    const float* __restrict__ lead, const float* __restrict__ traj,
    const float* __restrict__ hidden,
    const float* __restrict__ W_k, const float* __restrict__ W_r,
    const float* __restrict__ b_l, const float* __restrict__ W_d,
    const float* __restrict__ b_d, const float* __restrict__ W_lc,
    const float* __restrict__ b_lc,
    float* __restrict__ out_lc, float* __restrict__ out_h, float* __restrict__ out_c)
{
    // row[grp][buf][v]: 40 shorts (80 B): [0..11]=x, [12..31]=h, [32..39]=pad.
    __shared__ alignas(16) unsigned short row[G][2][16][40];

    const int tid  = threadIdx.x;
    const int wid  = tid >> 6;
    const int lane = tid & 63;
    const int q    = lane >> 4;
    const int v    = lane & 15;

    int gv[G];
    #pragma unroll
    for (int g = 0; g < G; ++g) gv[g] = blockIdx.x * (16 * G) + g * 16 + v;

    const int ntile = (wid < 2) ? 2 : (wid == 2) ? 1 : 0;

    // ---- z-MFMA fragments (w0..w2): A = W^T permuted, bias as C (shared
    // across groups); per-group h/c state.
    bf16x8 aW[2]; f32x4 cB[2];
    float h32[G][2], cst[G][2];
    int uu[2];
    #pragma unroll
    for (int l = 0; l < 2; ++l) {
        if (l < ntile) {
            const int tt = 2 * wid + l;
            #pragma unroll
            for (int j = 0; j < 8; ++j) {
                int k  = q * 8 + j;
                int qv = v >> 2, rv = v & 3;
                int u  = (tt < 4) ? (8 * (tt >> 1) + 2 * qv + (tt & 1)) : (16 + qv);
                int col = rv * 20 + u;
                float w = (k < 12) ? W_k[k * 80 + col] : W_r[(k - 12) * 80 + col];
                aW[l][j] = (short)f2bf(w);
            }
            uu[l] = (tt < 4) ? (8 * (tt >> 1) + 2 * q + (tt & 1)) : (16 + q);
            #pragma unroll
            for (int reg = 0; reg < 4; ++reg)
                cB[l][reg] = b_l[reg * 20 + uu[l]];
            #pragma unroll
            for (int g = 0; g < G; ++g) {
                h32[g][l] = hidden[(size_t)gv[g] * 20 + uu[l]];
                cst[g][l] = hidden[(size_t)NVEH * 20 + (size_t)gv[g] * 20 + uu[l]];
            }
        }
    }

    // ---- initial h publish into buf 0
    #pragma unroll
    for (int g = 0; g < G; ++g) {
        if (wid < 2) {
            unsigned pk = cvtpk_bf16(h32[g][0], h32[g][1]);
            *(unsigned*)&row[g][0][v][12 + 8 * wid + 2 * q] = pk;
        } else if (wid == 2) {
            row[g][0][v][28 + q] = f2bf(h32[g][0]);
        }
    }

    // ---- w3-only consts + x(0)/x(1) + prefetch
    const float* lf[G]; const float* ps[G]; float* lcout[G];
    #pragma unroll
    for (int g = 0; g < G; ++g) {
        lf[g]    = lead + (size_t)gv[g] * NT * 12;
        ps[g]    = traj + (size_t)gv[g] * NT;
        lcout[g] = out_lc + (size_t)gv[g] * NT * 3;
    }

    bf16x8 aH = {}; f32x4 cD = {};
    float wlc[4][3] = {}; float pb0[3] = {};
    float Ac[4], Bc[4];
    float4 rA[G], rB[G], rC[G];
    float pA[G], pB[G], pC[G];
    #pragma unroll
    for (int g = 0; g < G; ++g) {
        rA[g] = make_float4(0.f,0.f,0.f,0.f); rB[g] = rA[g]; rC[g] = rA[g];
        pA[g] = pB[g] = pC[g] = 0.f;
    }
    if (wid == 3) {
        #pragma unroll
        for (int j = 0; j < 8; ++j) {
            int k = q * 8 + j;
            aH[j] = (v < 10 && k >= 12) ? (short)f2bf(W_d[(k - 12) * 10 + v]) : (short)0;
        }
        #pragma unroll
        for (int reg = 0; reg < 4; ++reg) {
            int m = 4 * q + reg;
            cD[reg] = (m < 10) ? b_d[m] : 0.0f;
            #pragma unroll
            for (int j = 0; j < 3; ++j)
                wlc[reg][j] = (m < 10) ? W_lc[m * 3 + j] : 0.0f;
        }
        #pragma unroll
        for (int j = 0; j < 3; ++j) pb0[j] = (q == 0) ? b_lc[j] : 0.0f;

        #pragma unroll
        for (int i = 0; i < 4; ++i) {
            int e = 4 * q + i;
            if (e < 3)      { Ac[i] =  0.01f;  Bc[i] = -0.01f; }
            else if (e < 6) { Ac[i] = -0.01f;  Bc[i] =  0.01f; }
            else            { Ac[i] =  0.025f; Bc[i] =  0.0f;  }
        }

        // x(0) -> row[g][0], x(1) -> row[g][1]
        #pragma unroll
        for (int g = 0; g < G; ++g) {
            #pragma unroll
            for (int s = 0; s < 2; ++s) {
                float4 r0 = make_float4(0.f,0.f,0.f,0.f); float p0s = 0.f;
                if (q < 3) r0 = *(const float4*)(lf[g] + 12 * s + q * 4);
                if (q < 2) p0s = ps[g][s];
                if (q < 3) {
                    float xv[4] = { r0.x, r0.y, r0.z, r0.w };
                    #pragma unroll
                    for (int i = 0; i < 4; ++i) {
                        float x = fmaf(xv[i], Ac[i], p0s * Bc[i]);
                        xv[i] = (x == x) ? x : 1.0f;
                    }
                    unsigned pk0 = (unsigned)f2bf(xv[0]) | ((unsigned)f2bf(xv[1]) << 16);
                    unsigned pk1 = (unsigned)f2bf(xv[2]) | ((unsigned)f2bf(xv[3]) << 16);
                    *(uint2*)&row[g][s][v][4 * q] = make_uint2(pk0, pk1);
                }
            }
            // depth-3 prefetch of x(2), x(3), x(4)
            if (q < 3) {
                rA[g] = *(const float4*)(lf[g] + 12 * 2 + q * 4);
                rB[g] = *(const float4*)(lf[g] + 12 * 3 + q * 4);
                rC[g] = *(const float4*)(lf[g] + 12 * 4 + q * 4);
            }
            if (q < 2) { pA[g] = ps[g][2]; pB[g] = ps[g][3]; pC[g] = ps[g][4]; }
        }
    }

    lds_barrier();
    bf16x8 bx[G];
    #pragma unroll
    for (int g = 0; g < G; ++g) bx[g] = *(const bf16x8*)&row[g][0][v][8 * q];

    for (int t = 0; t < NT; ++t) {
        const int nxt = (t + 1) & 1;

        // ---- pre-barrier: z-MFMA + gates + publish (w0..w2), both groups.
        if (wid < 3) {
            f32x4 z0[G], z1[G];
            #pragma unroll
            for (int g = 0; g < G; ++g) {
                z0[g] = __builtin_amdgcn_mfma_f32_16x16x32_bf16(aW[0], bx[g], cB[0], 0, 0, 0);
                if (ntile == 2)
                    z1[g] = __builtin_amdgcn_mfma_f32_16x16x32_bf16(aW[1], bx[g], cB[1], 0, 0, 0);
            }
            #pragma unroll
            for (int g = 0; g < G; ++g) {
                {
                    float si = fsig(z0[g][0]);
                    float sf = fsig(z0[g][1]);
                    float tg = ftanh(z0[g][2]);
                    float so = fsig(z0[g][3]);
                    float cn = fmaf(sf, cst[g][0], si * tg);
                    cst[g][0] = cn;
                    h32[g][0] = so * ftanh(cn);
                }
                if (ntile == 2) {
                    float si = fsig(z1[g][0]);
                    float sf = fsig(z1[g][1]);
                    float tg = ftanh(z1[g][2]);
                    float so = fsig(z1[g][3]);
                    float cn = fmaf(sf, cst[g][1], si * tg);
                    cst[g][1] = cn;
                    h32[g][1] = so * ftanh(cn);
                }
                if (wid < 2) {
                    unsigned pk = cvtpk_bf16(h32[g][0], h32[g][1]);
                    *(unsigned*)&row[g][nxt][v][12 + 8 * wid + 2 * q] = pk;
                } else {
                    row[g][nxt][v][28 + q] = f2bf(h32[g][0]);
                }
            }
        }

        lds_barrier();
        bf16x8 bxn[G];
        #pragma unroll
        for (int g = 0; g < G; ++g)
            bxn[g] = *(const bf16x8*)&row[g][nxt][v][8 * q];

        // ---- post-barrier: w3 head + lc + store + x-pack(t+2) + prefetch,
        // overlapping w0..w2's next-step MFMA+gates.
        if (wid == 3) {
            #pragma unroll
            for (int g = 0; g < G; ++g) {
                f32x4 d = __builtin_amdgcn_mfma_f32_16x16x32_bf16(aH, bxn[g], cD, 0, 0, 0);
                float dr[4];
                #pragma unroll
                for (int reg = 0; reg < 4; ++reg) dr[reg] = fmaxf(d[reg], 0.0f);
                float p[3];
                #pragma unroll
                for (int j = 0; j < 3; ++j) {
                    float acc = pb0[j];
                    #pragma unroll
                    for (int reg = 0; reg < 4; ++reg) acc = fmaf(dr[reg], wlc[reg][j], acc);
                    acc += __shfl_xor(acc, 16);
                    acc += __shfl_xor(acc, 32);
                    p[j] = acc;
                }
                if (q == (t & 3)) {
                    float* o = lcout[g] + (size_t)t * 3;
                    *(float2*)o = make_float2(p[0], p[1]);
                    o[2] = p[2];
                }

                // x-pack for step t+2 into row[g][t&1] (readers drained at the
                // barrier just passed; next read after the NEXT barrier).
                if (q < 3) {
                    float xv[4] = { rA[g].x, rA[g].y, rA[g].z, rA[g].w };
                    #pragma unroll
                    for (int i = 0; i < 4; ++i) {
                        float x = fmaf(xv[i], Ac[i], pA[g] * Bc[i]);
                        xv[i] = (x == x) ? x : 1.0f;
                    }
                    unsigned pk0 = (unsigned)f2bf(xv[0]) | ((unsigned)f2bf(xv[1]) << 16);
                    unsigned pk1 = (unsigned)f2bf(xv[2]) | ((unsigned)f2bf(xv[3]) << 16);
                    *(uint2*)&row[g][t & 1][v][4 * q] = make_uint2(pk0, pk1);
                }
                rA[g] = rB[g]; rB[g] = rC[g]; pA[g] = pB[g]; pB[g] = pC[g];
                int tn = (t + 5 < NT) ? (t + 5) : (NT - 1);
                if (q < 3) rC[g] = *(const float4*)(lf[g] + 12 * tn + q * 4);
                if (q < 2) pC[g] = ps[g][tn];
            }
        }

        #pragma unroll
        for (int g = 0; g < G; ++g) bx[g] = bxn[g];
    }

    if (wid < 3) {
        #pragma unroll
        for (int g = 0; g < G; ++g) {
            #pragma unroll
            for (int l = 0; l < 2; ++l) {
                if (l < ntile) {
                    out_h[(size_t)gv[g] * 20 + uu[l]] = h32[g][l];
                    out_c[(size_t)gv[g] * 20 + uu[l]] = cst[g][l];
                }
            }
        }
    }
}

extern "C" void kernel_launch(void* const* d_in, const int* in_sizes, int n_in,
                              void* d_out, int out_size, void* d_ws, size_t ws_size,
                              hipStream_t stream) {
    const float* lead   = (const float*)d_in[0];
    const float* traj   = (const float*)d_in[1];
    const float* hidden = (const float*)d_in[2];
    const float* W_k    = (const float*)d_in[3];
    const float* W_r    = (const float*)d_in[4];
    const float* b_l    = (const float*)d_in[5];
    const float* W_d    = (const float*)d_in[6];
    const float* b_d    = (const float*)d_in[7];
    const float* W_lc   = (const float*)d_in[8];
    const float* b_lc   = (const float*)d_in[9];

    float* out    = (float*)d_out;
    float* out_tt = out;
    float* out_lc = out + (size_t)NVEH * NT;
    float* out_h  = out_lc + (size_t)NVEH * NT * 3;
    float* out_c  = out_h + (size_t)NVEH * 20;

    hipMemcpyAsync(out_tt, traj, (size_t)NVEH * NT * sizeof(float),
                   hipMemcpyDeviceToDevice, stream);

    lstm_scan_kernel<<<dim3(NVEH / (16 * G)), dim3(256), 0, stream>>>(
        lead, traj, hidden, W_k, W_r, b_l, W_d, b_d, W_lc, b_lc,
        out_lc, out_h, out_c);
}

// Round 4
// 657.577 us; speedup vs baseline: 1.1757x; 1.1757x over previous
//
#include <hip/hip_runtime.h>

#define NVEH 8192
#define NT   512

typedef short bf16x8 __attribute__((ext_vector_type(8)));
typedef float f32x4  __attribute__((ext_vector_type(4)));

__device__ __forceinline__ float fsig(float x) {
    float e = __builtin_amdgcn_exp2f(-1.44269504f * x);
    return __builtin_amdgcn_rcpf(1.0f + e);
}
__device__ __forceinline__ float ftanh(float x) {
    float e = __builtin_amdgcn_exp2f(-2.88539008f * x);
    return 2.0f * __builtin_amdgcn_rcpf(1.0f + e) - 1.0f;
}
__device__ __forceinline__ unsigned short f2bf(float f) {
    union { float f; unsigned u; } vv; vv.f = f;
    unsigned r = vv.u + 0x7fff + ((vv.u >> 16) & 1);
    return (unsigned short)(r >> 16);
}
// HW packed f32->bf16 (RNE), one instr for two converts + pack.
__device__ __forceinline__ unsigned cvtpk_bf16(float lo, float hi) {
    unsigned r;
    asm("v_cvt_pk_bf16_f32 %0, %1, %2" : "=v"(r) : "v"(lo), "v"(hi));
    return r;
}

// LDS-only barrier: order ds ops across waves WITHOUT draining vmcnt.
__device__ __forceinline__ void lds_barrier() {
    asm volatile("s_waitcnt lgkmcnt(0)" ::: "memory");
    __builtin_amdgcn_s_barrier();
    asm volatile("" ::: "memory");
}

// 6 waves per 16-vehicle chain (384-thread block, 512 blocks -> 2 blocks/CU,
// 3 waves/SIMD). Gate waves w0..w4 each own ONE z-tile (units 4*wid..4*wid+3):
// pre-barrier = ds_read -> 1 MFMA -> 1 unit's gates (10 trans) -> b16 publish.
// Service wave w5 runs entirely post-barrier: head MFMA + lc + store +
// x-pack(t+2) + depth-3 global prefetch. One LDS barrier per step.
__global__ __launch_bounds__(384) void lstm_scan_kernel(
    const float* __restrict__ lead, const float* __restrict__ traj,
    const float* __restrict__ hidden,
    const float* __restrict__ W_k, const float* __restrict__ W_r,
    const float* __restrict__ b_l, const float* __restrict__ W_d,
    const float* __restrict__ b_d, const float* __restrict__ W_lc,
    const float* __restrict__ b_lc,
    float* __restrict__ out_lc, float* __restrict__ out_h, float* __restrict__ out_c)
{
    // row[buf][v]: 40 shorts (80 B): [0..11]=x, [12..31]=h, [32..39]=pad.
    __shared__ alignas(16) unsigned short row[2][16][40];

    const int tid  = threadIdx.x;
    const int wid  = tid >> 6;      // 0..5
    const int lane = tid & 63;
    const int q    = lane >> 4;
    const int v    = lane & 15;
    const int gv   = blockIdx.x * 16 + v;

    // ---- gate waves: A = W^T rows for tile wid (unit u = 4*wid + (r>>2),
    // gate g = r&3 at within-tile row r), bias as C. One unit per lane.
    bf16x8 aW = {}; f32x4 cB = {};
    float h32 = 0.0f, cst = 0.0f;
    int uu = 0;
    if (wid < 5) {
        const int tt = wid;
        #pragma unroll
        for (int j = 0; j < 8; ++j) {
            int k  = q * 8 + j;              // A: lane (q,v) holds row v, k=8q+j
            int qv = v >> 2, rv = v & 3;
            int u  = 4 * tt + qv;
            int col = rv * 20 + u;           // keras gate-major [i|f|c|o]
            float w = (k < 12) ? W_k[k * 80 + col] : W_r[(k - 12) * 80 + col];
            aW[j] = (short)f2bf(w);
        }
        uu = 4 * tt + q;                     // C: lane (q,v) = rows 4q..4q+3, col v
        #pragma unroll
        for (int reg = 0; reg < 4; ++reg)
            cB[reg] = b_l[reg * 20 + uu];
        h32 = hidden[(size_t)gv * 20 + uu];
        cst = hidden[(size_t)NVEH * 20 + (size_t)gv * 20 + uu];
        row[0][v][12 + uu] = f2bf(h32);      // initial h publish
    }

    // ---- service wave consts + x(0)/x(1) + prefetch
    const float* lf = lead + (size_t)gv * NT * 12;
    const float* ps = traj + (size_t)gv * NT;
    float* lcout    = out_lc + (size_t)gv * NT * 3;

    bf16x8 aH = {}; f32x4 cD = {};
    float wlc[4][3] = {}; float pb0[3] = {};
    float Ac[4], Bc[4];
    float4 rA = make_float4(0.f,0.f,0.f,0.f), rB = rA, rC = rA;
    float pA = 0.f, pB = 0.f, pC = 0.f;
    if (wid == 5) {
        #pragma unroll
        for (int j = 0; j < 8; ++j) {
            int k = q * 8 + j;
            aH[j] = (v < 10 && k >= 12) ? (short)f2bf(W_d[(k - 12) * 10 + v]) : (short)0;
        }
        #pragma unroll
        for (int reg = 0; reg < 4; ++reg) {
            int m = 4 * q + reg;
            cD[reg] = (m < 10) ? b_d[m] : 0.0f;
            #pragma unroll
            for (int j = 0; j < 3; ++j)
                wlc[reg][j] = (m < 10) ? W_lc[m * 3 + j] : 0.0f;
        }
        #pragma unroll
        for (int j = 0; j < 3; ++j) pb0[j] = (q == 0) ? b_lc[j] : 0.0f;

        #pragma unroll
        for (int i = 0; i < 4; ++i) {
            int e = 4 * q + i;
            if (e < 3)      { Ac[i] =  0.01f;  Bc[i] = -0.01f; }
            else if (e < 6) { Ac[i] = -0.01f;  Bc[i] =  0.01f; }
            else            { Ac[i] =  0.025f; Bc[i] =  0.0f;  }
        }

        // x(0) -> row[0], x(1) -> row[1]
        #pragma unroll
        for (int s = 0; s < 2; ++s) {
            float4 r0 = make_float4(0.f,0.f,0.f,0.f); float p0s = 0.f;
            if (q < 3) r0 = *(const float4*)(lf + 12 * s + q * 4);
            if (q < 2) p0s = ps[s];
            if (q < 3) {
                float xv[4] = { r0.x, r0.y, r0.z, r0.w };
                #pragma unroll
                for (int i = 0; i < 4; ++i) {
                    float x = fmaf(xv[i], Ac[i], p0s * Bc[i]);
                    xv[i] = (x == x) ? x : 1.0f;
                }
                *(uint2*)&row[s][v][4 * q] =
                    make_uint2(cvtpk_bf16(xv[0], xv[1]), cvtpk_bf16(xv[2], xv[3]));
            }
        }
        // depth-3 prefetch of x(2), x(3), x(4)
        if (q < 3) {
            rA = *(const float4*)(lf + 12 * 2 + q * 4);
            rB = *(const float4*)(lf + 12 * 3 + q * 4);
            rC = *(const float4*)(lf + 12 * 4 + q * 4);
        }
        if (q < 2) { pA = ps[2]; pB = ps[3]; pC = ps[4]; }
    }

    lds_barrier();
    bf16x8 bx = *(const bf16x8*)&row[0][v][8 * q];

    for (int t = 0; t < NT; ++t) {
        const int nxt = (t + 1) & 1;

        // ---- pre-barrier: one z-MFMA + one unit's gates + b16 publish
        if (wid < 5) {
            f32x4 z = __builtin_amdgcn_mfma_f32_16x16x32_bf16(aW, bx, cB, 0, 0, 0);
            float si = fsig(z[0]);
            float sf = fsig(z[1]);
            float tg = ftanh(z[2]);
            float so = fsig(z[3]);
            float cn = fmaf(sf, cst, si * tg);
            cst = cn;
            h32 = so * ftanh(cn);
            row[nxt][v][12 + uu] = f2bf(h32);
        }

        lds_barrier();
        // gather next B-frag (x_{t+1} | h_t): one aligned b128 per lane
        bf16x8 bxn = *(const bf16x8*)&row[nxt][v][8 * q];

        // ---- post-barrier: service wave overlaps gate waves' next step.
        if (wid == 5) {
            f32x4 d = __builtin_amdgcn_mfma_f32_16x16x32_bf16(aH, bxn, cD, 0, 0, 0);
            float dr[4];
            #pragma unroll
            for (int reg = 0; reg < 4; ++reg) dr[reg] = fmaxf(d[reg], 0.0f);
            float p[3];
            #pragma unroll
            for (int j = 0; j < 3; ++j) {
                float acc = pb0[j];
                #pragma unroll
                for (int reg = 0; reg < 4; ++reg) acc = fmaf(dr[reg], wlc[reg][j], acc);
                acc += __shfl_xor(acc, 16);
                acc += __shfl_xor(acc, 32);
                p[j] = acc;
            }
            if (q == (t & 3)) {
                float* o = lcout + (size_t)t * 3;
                *(float2*)o = make_float2(p[0], p[1]);
                o[2] = p[2];
            }

            // x-pack for step t+2 into row[t&1] (readers of that buffer
            // drained at the barrier just passed; next read after the NEXT
            // barrier, which also orders this write).
            if (q < 3) {
                float xv[4] = { rA.x, rA.y, rA.z, rA.w };
                #pragma unroll
                for (int i = 0; i < 4; ++i) {
                    float x = fmaf(xv[i], Ac[i], pA * Bc[i]);
                    xv[i] = (x == x) ? x : 1.0f;
                }
                *(uint2*)&row[t & 1][v][4 * q] =
                    make_uint2(cvtpk_bf16(xv[0], xv[1]), cvtpk_bf16(xv[2], xv[3]));
            }
            rA = rB; rB = rC; pA = pB; pB = pC;
            int tn = (t + 5 < NT) ? (t + 5) : (NT - 1);
            if (q < 3) rC = *(const float4*)(lf + 12 * tn + q * 4);
            if (q < 2) pC = ps[tn];
        }

        bx = bxn;
    }

    if (wid < 5) {
        out_h[(size_t)gv * 20 + uu] = h32;
        out_c[(size_t)gv * 20 + uu] = cst;
    }
}

extern "C" void kernel_launch(void* const* d_in, const int* in_sizes, int n_in,
                              void* d_out, int out_size, void* d_ws, size_t ws_size,
                              hipStream_t stream) {
    const float* lead   = (const float*)d_in[0];
    const float* traj   = (const float*)d_in[1];
    const float* hidden = (const float*)d_in[2];
    const float* W_k    = (const float*)d_in[3];
    const float* W_r    = (const float*)d_in[4];
    const float* b_l    = (const float*)d_in[5];
    const float* W_d    = (const float*)d_in[6];
    const float* b_d    = (const float*)d_in[7];
    const float* W_lc   = (const float*)d_in[8];
    const float* b_lc   = (const float*)d_in[9];

    float* out    = (float*)d_out;
    float* out_tt = out;
    float* out_lc = out + (size_t)NVEH * NT;
    float* out_h  = out_lc + (size_t)NVEH * NT * 3;
    float* out_c  = out_h + (size_t)NVEH * 20;

    hipMemcpyAsync(out_tt, traj, (size_t)NVEH * NT * sizeof(float),
                   hipMemcpyDeviceToDevice, stream);

    lstm_scan_kernel<<<dim3(NVEH / 16), dim3(384), 0, stream>>>(
        lead, traj, hidden, W_k, W_r, b_l, W_d, b_d, W_lc, b_lc,
        out_lc, out_h, out_c);
}